// Round 1
// baseline (4869.477 us; speedup 1.0000x reference)
//
#include <hip/hip_runtime.h>
#include <math.h>

#define BB 128
#define NN 256
#define DD 64
constexpr int NROWS = BB * NN; // 32768

// ---------------- 1. L2 normalize (one wave per row of 64) ----------------
__global__ __launch_bounds__(256) void norm_kernel(const float* __restrict__ inp,
                                                   const float* __restrict__ tgin,
                                                   float* __restrict__ ipn,
                                                   float* __restrict__ tgn) {
  int wid = threadIdx.x >> 6;
  int lane = threadIdx.x & 63;
  int row = blockIdx.x * 4 + wid;   // 0 .. 2*NROWS-1
  const float* src;
  float* dst;
  int r = row;
  if (row < NROWS) { src = inp; dst = ipn; }
  else { src = tgin; dst = tgn; r = row - NROWS; }
  float x = src[(size_t)r * DD + lane];
  float s = x * x;
  #pragma unroll
  for (int off = 32; off; off >>= 1) s += __shfl_xor(s, off);
  float nrm = sqrtf(s);
  float scale = 1.0f / fmaxf(nrm, 1e-12f);
  dst[(size_t)r * DD + lane] = x * scale;
}

// ---------------- 2. batched fp32 GEMM: 64x64 tile, K=64 ----------------
// z=0: Out=cos = ip @ tg^T ; z=1: Out=self = ip @ ip^T
__global__ __launch_bounds__(256) void gemm_kernel(const float* __restrict__ ipn,
                                                   const float* __restrict__ tgn,
                                                   float* __restrict__ cosm,
                                                   float* __restrict__ selfm) {
  __shared__ float As[64 * 64];  // [k][row] transposed
  __shared__ float Bs[64 * 64];
  int b = blockIdx.y;
  int ti = (blockIdx.x >> 2) * 64;
  int tj = (blockIdx.x & 3) * 64;
  const float* A = ipn + (size_t)b * NN * DD + (size_t)ti * DD;
  const float* Bm = (blockIdx.z ? ipn : tgn) + (size_t)b * NN * DD + (size_t)tj * DD;
  float* Out = (blockIdx.z ? selfm : cosm) + (size_t)b * NN * NN;
  int t = threadIdx.x;
  #pragma unroll
  for (int i = 0; i < 4; ++i) {
    int f4 = t + 256 * i;          // float4 index, 1024 total
    int row = f4 >> 4;             // 16 float4 per row
    int k0 = (f4 & 15) << 2;
    float4 a = reinterpret_cast<const float4*>(A)[f4];
    float4 v = reinterpret_cast<const float4*>(Bm)[f4];
    As[(k0 + 0) * 64 + row] = a.x; As[(k0 + 1) * 64 + row] = a.y;
    As[(k0 + 2) * 64 + row] = a.z; As[(k0 + 3) * 64 + row] = a.w;
    Bs[(k0 + 0) * 64 + row] = v.x; Bs[(k0 + 1) * 64 + row] = v.y;
    Bs[(k0 + 2) * 64 + row] = v.z; Bs[(k0 + 3) * 64 + row] = v.w;
  }
  __syncthreads();
  int tx = t & 15, ty = t >> 4;
  float acc[4][4] = {};
  #pragma unroll 8
  for (int k = 0; k < 64; ++k) {
    float4 av = *reinterpret_cast<const float4*>(&As[k * 64 + ty * 4]);
    float4 bv = *reinterpret_cast<const float4*>(&Bs[k * 64 + tx * 4]);
    float ar[4] = {av.x, av.y, av.z, av.w};
    float br[4] = {bv.x, bv.y, bv.z, bv.w};
    #pragma unroll
    for (int r = 0; r < 4; ++r)
      #pragma unroll
      for (int c = 0; c < 4; ++c)
        acc[r][c] = fmaf(ar[r], br[c], acc[r][c]);
  }
  #pragma unroll
  for (int r = 0; r < 4; ++r) {
    float4 o = {acc[r][0], acc[r][1], acc[r][2], acc[r][3]};
    *reinterpret_cast<float4*>(&Out[(size_t)(ti + ty * 4 + r) * NN + tj + tx * 4]) = o;
  }
}

// ---------------- 3. Jonker-Volgenant LSAP, one block per batch ----------------
// cost = -cos. Exact port of the reference (1-based cols, fp64 duals).
__global__ __launch_bounds__(256) void hungarian_kernel(const float* __restrict__ cosm,
                                                        int* __restrict__ tgt) {
  const int b = blockIdx.x;
  const float* C = cosm + (size_t)b * NN * NN;
  __shared__ double u[NN + 1];
  __shared__ double v[NN + 1];
  __shared__ double minv[NN + 1];
  __shared__ int way[NN + 1];
  __shared__ int p[NN + 1];
  __shared__ unsigned char used[NN + 1];
  __shared__ double rv[4];
  __shared__ int ri[4];
  __shared__ double s_delta;
  __shared__ int s_j1;
  const int t = threadIdx.x;
  const int jc = t + 1;          // this thread's column (1-based)
  const int lane = t & 63, wid = t >> 6;
  u[jc] = 0.0; v[jc] = 0.0; p[jc] = 0;
  if (t == 0) { u[0] = 0.0; v[0] = 0.0; p[0] = 0; }
  __syncthreads();
  for (int i = 1; i <= NN; ++i) {
    if (t == 0) p[0] = i;
    minv[jc] = (double)INFINITY;
    used[jc] = 0;
    if (t == 0) used[0] = 0;
    __syncthreads();
    int j0 = 0;
    while (true) {
      if (t == 0) used[j0] = 1;
      __syncthreads();                      // (A)
      int i0 = p[j0];
      double cand;
      if (!used[jc]) {
        double cur = -(double)C[(size_t)(i0 - 1) * NN + (jc - 1)] - u[i0] - v[jc];
        if (cur < minv[jc]) { minv[jc] = cur; way[jc] = j0; }
        cand = minv[jc];
      } else {
        cand = (double)INFINITY;
      }
      // 256-wide lexicographic argmin (first-index tiebreak = np.argmin)
      double bvv = cand; int bii = jc;
      #pragma unroll
      for (int off = 32; off; off >>= 1) {
        double ov = __shfl_xor(bvv, off);
        int oi = __shfl_xor(bii, off);
        if (ov < bvv || (ov == bvv && oi < bii)) { bvv = ov; bii = oi; }
      }
      if (lane == 0) { rv[wid] = bvv; ri[wid] = bii; }
      __syncthreads();                      // (B)
      if (t == 0) {
        double fv = rv[0]; int fi = ri[0];
        #pragma unroll
        for (int w = 1; w < 4; ++w)
          if (rv[w] < fv || (rv[w] == fv && ri[w] < fi)) { fv = rv[w]; fi = ri[w]; }
        s_delta = fv; s_j1 = fi;
      }
      __syncthreads();                      // (C)
      double delta = s_delta;
      int j1 = s_j1;
      if (t == 0) u[p[0]] += delta;                      // virtual col 0 (always used)
      if (used[jc]) { u[p[jc]] += delta; v[jc] -= delta; }
      else minv[jc] -= delta;
      int pj1 = p[j1];
      j0 = j1;
      if (pj1 == 0) break;
      __syncthreads();                      // (D) duals visible next iter
    }
    __syncthreads();                        // way[]/dual writes visible
    if (t == 0) {
      int j = j0;
      while (j != 0) {
        int jp = way[j];
        p[j] = (jp == 0) ? i : p[jp];
        j = jp;
      }
    }
    __syncthreads();
  }
  // col4row[p[j]-1] = j-1
  tgt[(size_t)b * NN + (p[jc] - 1)] = jc - 1;
}

// ---------------- 4. fused log-softmax + NLL (one wave per row) ----------------
__global__ __launch_bounds__(256) void nll_kernel(const float* __restrict__ cosm,
                                                  const float* __restrict__ selfm,
                                                  const int* __restrict__ tgt,
                                                  float* __restrict__ nll) {
  int lane = threadIdx.x & 63, wid = threadIdx.x >> 6;
  int row = blockIdx.x * 4 + wid;           // 0..NROWS-1
  int r = row & (NN - 1);
  const float* crow = cosm + (size_t)row * NN;
  const float* srow = selfm + (size_t)row * NN;
  float xc[4], xs[4];
  float m = -INFINITY;
  #pragma unroll
  for (int q = 0; q < 4; ++q) {
    int j = lane + 64 * q;
    xc[q] = crow[j];
    xs[q] = (j == r) ? -INFINITY : srow[j];
    m = fmaxf(m, fmaxf(xc[q], xs[q]));
  }
  #pragma unroll
  for (int off = 32; off; off >>= 1) m = fmaxf(m, __shfl_xor(m, off));
  float s = 0.f;
  #pragma unroll
  for (int q = 0; q < 4; ++q) {
    s += expf(xc[q] - m);
    s += (xs[q] == -INFINITY) ? 0.f : expf(xs[q] - m);
  }
  #pragma unroll
  for (int off = 32; off; off >>= 1) s += __shfl_xor(s, off);
  if (lane == 0) {
    float lse = m + logf(s);
    nll[row] = lse - crow[tgt[row]];
  }
}

// ---------------- 5. deterministic mean reduce ----------------
__global__ __launch_bounds__(256) void reduce_kernel(const float* __restrict__ nll,
                                                     float* __restrict__ out) {
  __shared__ float sm[256];
  int t = threadIdx.x;
  float s = 0.f;
  for (int i = t; i < NROWS; i += 256) s += nll[i];
  sm[t] = s;
  __syncthreads();
  for (int st = 128; st; st >>= 1) {
    if (t < st) sm[t] += sm[t + st];
    __syncthreads();
  }
  if (t == 0) out[0] = sm[0] / (float)NROWS;
}

extern "C" void kernel_launch(void* const* d_in, const int* in_sizes, int n_in,
                              void* d_out, int out_size, void* d_ws, size_t ws_size,
                              hipStream_t stream) {
  const float* inputs = (const float*)d_in[0];
  const float* targets = (const float*)d_in[1];
  float* ws = (float*)d_ws;
  float* ipn = ws;                                   // 2,097,152 f
  float* tgn = ipn + (size_t)BB * NN * DD;           // 2,097,152 f
  float* cosm = tgn + (size_t)BB * NN * DD;          // 8,388,608 f
  float* selfm = cosm + (size_t)BB * NN * NN;        // 8,388,608 f
  int* tgt = (int*)(selfm + (size_t)BB * NN * NN);   // 32,768 i
  float* nll = (float*)(tgt + BB * NN);              // 32,768 f

  norm_kernel<<<2 * NROWS / 4, 256, 0, stream>>>(inputs, targets, ipn, tgn);
  gemm_kernel<<<dim3(16, BB, 2), 256, 0, stream>>>(ipn, tgn, cosm, selfm);
  hungarian_kernel<<<BB, 256, 0, stream>>>(cosm, tgt);
  nll_kernel<<<NROWS / 4, 256, 0, stream>>>(cosm, selfm, tgt, nll);
  reduce_kernel<<<1, 256, 0, stream>>>(nll, (float*)d_out);
}

// Round 2
// 3142.032 us; speedup vs baseline: 1.5498x; 1.5498x over previous
//
#include <hip/hip_runtime.h>
#include <math.h>

#define BB 128
#define NN 256
#define DD 64
constexpr int NROWS = BB * NN; // 32768

// ---------------- 1. L2 normalize (one wave per row of 64) ----------------
__global__ __launch_bounds__(256) void norm_kernel(const float* __restrict__ inp,
                                                   const float* __restrict__ tgin,
                                                   float* __restrict__ ipn,
                                                   float* __restrict__ tgn) {
  int wid = threadIdx.x >> 6;
  int lane = threadIdx.x & 63;
  int row = blockIdx.x * 4 + wid;   // 0 .. 2*NROWS-1
  const float* src;
  float* dst;
  int r = row;
  if (row < NROWS) { src = inp; dst = ipn; }
  else { src = tgin; dst = tgn; r = row - NROWS; }
  float x = src[(size_t)r * DD + lane];
  float s = x * x;
  #pragma unroll
  for (int off = 32; off; off >>= 1) s += __shfl_xor(s, off);
  float nrm = sqrtf(s);
  float scale = 1.0f / fmaxf(nrm, 1e-12f);
  dst[(size_t)r * DD + lane] = x * scale;
}

// ---------------- 2. batched fp32 GEMM: 64x64 tile, K=64 ----------------
__global__ __launch_bounds__(256) void gemm_kernel(const float* __restrict__ ipn,
                                                   const float* __restrict__ tgn,
                                                   float* __restrict__ cosm,
                                                   float* __restrict__ selfm) {
  __shared__ float As[64 * 64];  // [k][row] transposed
  __shared__ float Bs[64 * 64];
  int b = blockIdx.y;
  int ti = (blockIdx.x >> 2) * 64;
  int tj = (blockIdx.x & 3) * 64;
  const float* A = ipn + (size_t)b * NN * DD + (size_t)ti * DD;
  const float* Bm = (blockIdx.z ? ipn : tgn) + (size_t)b * NN * DD + (size_t)tj * DD;
  float* Out = (blockIdx.z ? selfm : cosm) + (size_t)b * NN * NN;
  int t = threadIdx.x;
  #pragma unroll
  for (int i = 0; i < 4; ++i) {
    int f4 = t + 256 * i;
    int row = f4 >> 4;
    int k0 = (f4 & 15) << 2;
    float4 a = reinterpret_cast<const float4*>(A)[f4];
    float4 v = reinterpret_cast<const float4*>(Bm)[f4];
    As[(k0 + 0) * 64 + row] = a.x; As[(k0 + 1) * 64 + row] = a.y;
    As[(k0 + 2) * 64 + row] = a.z; As[(k0 + 3) * 64 + row] = a.w;
    Bs[(k0 + 0) * 64 + row] = v.x; Bs[(k0 + 1) * 64 + row] = v.y;
    Bs[(k0 + 2) * 64 + row] = v.z; Bs[(k0 + 3) * 64 + row] = v.w;
  }
  __syncthreads();
  int tx = t & 15, ty = t >> 4;
  float acc[4][4] = {};
  #pragma unroll 8
  for (int k = 0; k < 64; ++k) {
    float4 av = *reinterpret_cast<const float4*>(&As[k * 64 + ty * 4]);
    float4 bv = *reinterpret_cast<const float4*>(&Bs[k * 64 + tx * 4]);
    float ar[4] = {av.x, av.y, av.z, av.w};
    float br[4] = {bv.x, bv.y, bv.z, bv.w};
    #pragma unroll
    for (int r = 0; r < 4; ++r)
      #pragma unroll
      for (int c = 0; c < 4; ++c)
        acc[r][c] = fmaf(ar[r], br[c], acc[r][c]);
  }
  #pragma unroll
  for (int r = 0; r < 4; ++r) {
    float4 o = {acc[r][0], acc[r][1], acc[r][2], acc[r][3]};
    *reinterpret_cast<float4*>(&Out[(size_t)(ti + ty * 4 + r) * NN + tj + tx * 4]) = o;
  }
}

// ---------------- 3. Jonker-Volgenant LSAP: ONE WAVE per batch ----------------
// Absolute-distance formulation (scipy-style), fp64. 4 cols/lane: col = lane*4+q.
// No __syncthreads (single wave). u[row] in LDS; everything else in registers.

__device__ __forceinline__ int sel4i(const int a[4], int q) {
  int r = a[0];
  if (q == 1) r = a[1];
  else if (q == 2) r = a[2];
  else if (q == 3) r = a[3];
  return r;
}
__device__ __forceinline__ void set4i(int a[4], int q, int v) {
  if (q == 0) a[0] = v;
  else if (q == 1) a[1] = v;
  else if (q == 2) a[2] = v;
  else a[3] = v;
}

__global__ __launch_bounds__(64) void hungarian_kernel(const float* __restrict__ cosm,
                                                       int* __restrict__ tgt) {
  const int b = blockIdx.x;
  const float* __restrict__ C = cosm + (size_t)b * NN * NN;
  __shared__ double u_lds[NN];          // dual per ROW (0-based)
  const int lane = threadIdx.x;         // 0..63
  const double DINF = (double)INFINITY;

  double v[4] = {0.0, 0.0, 0.0, 0.0};   // col duals (cols lane*4+q)
  int p[4] = {0, 0, 0, 0};              // row assigned to col (1-based, 0=free)
  #pragma unroll
  for (int q = 0; q < 4; ++q) u_lds[lane * 4 + q] = 0.0;

  for (int i = 1; i <= NN; ++i) {
    double minv[4] = {DINF, DINF, DINF, DINF};  // absolute shortest dist d(j)
    int way[4] = {-2, -2, -2, -2};
    int usedm = 0;
    double Delta = 0.0;                 // total distance so far
    int j0 = -1;                        // virtual start column
    double u_i0 = 0.0;                  // u of current row (phase row: 0)
    // current scan row = i
    float4 c4 = reinterpret_cast<const float4*>(C + (size_t)(i - 1) * NN)[lane];
    int jf;                             // final (free) column

    while (true) {
      float cc[4] = {c4.x, c4.y, c4.z, c4.w};
      double cand[4];
      #pragma unroll
      for (int q = 0; q < 4; ++q) {
        double dnew = Delta + (-(double)cc[q] - u_i0 - v[q]);
        bool freeq = !((usedm >> q) & 1);
        if (freeq && dnew < minv[q]) { minv[q] = dnew; way[q] = j0; }
        cand[q] = freeq ? minv[q] : DINF;
      }
      // local lexicographic argmin over 4 (ascending col keeps first index)
      double bv = cand[0]; int bc = lane * 4;
      #pragma unroll
      for (int q = 1; q < 4; ++q)
        if (cand[q] < bv) { bv = cand[q]; bc = lane * 4 + q; }
      // 64-lane lexicographic butterfly (first-index tiebreak = np.argmin)
      #pragma unroll
      for (int off = 32; off; off >>= 1) {
        double ov = __shfl_xor(bv, off);
        int oc = __shfl_xor(bc, off);
        if (ov < bv || (ov == bv && oc < bc)) { bv = ov; bc = oc; }
      }
      Delta = bv;
      int j1 = bc;
      // pnext = p[j1] via owner-lane shfl
      int psel = sel4i(p, j1 & 3);
      int pnext = __shfl(psel, j1 >> 2);
      // prefetch next scan row + its dual (u unchanged within phase)
      int rown = (pnext > 0 ? pnext : 1) - 1;
      float4 c4n = reinterpret_cast<const float4*>(C + (size_t)rown * NN)[lane];
      double u_n = u_lds[rown];
      if (pnext == 0) { jf = j1; break; }
      if ((j1 >> 2) == lane) usedm |= 1 << (j1 & 3);  // j1 joins used set
      j0 = j1;
      u_i0 = u_n;
      c4 = c4n;
    }

    // phase-end dual updates: used cols only (final col jf excluded)
    #pragma unroll
    for (int q = 0; q < 4; ++q) {
      if ((usedm >> q) & 1) {
        double dd = Delta - minv[q];
        v[q] -= dd;
        u_lds[p[q] - 1] += dd;          // distinct rows -> no collision
      }
    }
    if (lane == 0) u_lds[i - 1] = Delta;  // phase row: u was 0

    // augmentation walk (lockstep, register shfl broadcasts)
    int j = jf;
    while (true) {
      int wsel = sel4i(way, j & 3);
      int w = __shfl(wsel, j >> 2);       // way[j] (uniform)
      int newv;
      if (w < 0) newv = i;
      else {
        int ps = sel4i(p, w & 3);
        newv = __shfl(ps, w >> 2);        // old p[way[j]]
      }
      if ((j >> 2) == lane) set4i(p, j & 3, newv);
      if (w < 0) break;
      j = w;
    }
  }
  // col4row[p[j]-1] = j
  #pragma unroll
  for (int q = 0; q < 4; ++q)
    tgt[(size_t)b * NN + (p[q] - 1)] = lane * 4 + q;
}

// ---------------- 4. fused log-softmax + NLL (one wave per row) ----------------
__global__ __launch_bounds__(256) void nll_kernel(const float* __restrict__ cosm,
                                                  const float* __restrict__ selfm,
                                                  const int* __restrict__ tgt,
                                                  float* __restrict__ nll) {
  int lane = threadIdx.x & 63, wid = threadIdx.x >> 6;
  int row = blockIdx.x * 4 + wid;
  int r = row & (NN - 1);
  const float* crow = cosm + (size_t)row * NN;
  const float* srow = selfm + (size_t)row * NN;
  float xc[4], xs[4];
  float m = -INFINITY;
  #pragma unroll
  for (int q = 0; q < 4; ++q) {
    int j = lane + 64 * q;
    xc[q] = crow[j];
    xs[q] = (j == r) ? -INFINITY : srow[j];
    m = fmaxf(m, fmaxf(xc[q], xs[q]));
  }
  #pragma unroll
  for (int off = 32; off; off >>= 1) m = fmaxf(m, __shfl_xor(m, off));
  float s = 0.f;
  #pragma unroll
  for (int q = 0; q < 4; ++q) {
    s += expf(xc[q] - m);
    s += (xs[q] == -INFINITY) ? 0.f : expf(xs[q] - m);
  }
  #pragma unroll
  for (int off = 32; off; off >>= 1) s += __shfl_xor(s, off);
  if (lane == 0) {
    float lse = m + logf(s);
    nll[row] = lse - crow[tgt[row]];
  }
}

// ---------------- 5. deterministic mean reduce ----------------
__global__ __launch_bounds__(256) void reduce_kernel(const float* __restrict__ nll,
                                                     float* __restrict__ out) {
  __shared__ float sm[256];
  int t = threadIdx.x;
  float s = 0.f;
  for (int i = t; i < NROWS; i += 256) s += nll[i];
  sm[t] = s;
  __syncthreads();
  for (int st = 128; st; st >>= 1) {
    if (t < st) sm[t] += sm[t + st];
    __syncthreads();
  }
  if (t == 0) out[0] = sm[0] / (float)NROWS;
}

extern "C" void kernel_launch(void* const* d_in, const int* in_sizes, int n_in,
                              void* d_out, int out_size, void* d_ws, size_t ws_size,
                              hipStream_t stream) {
  const float* inputs = (const float*)d_in[0];
  const float* targets = (const float*)d_in[1];
  float* ws = (float*)d_ws;
  float* ipn = ws;
  float* tgn = ipn + (size_t)BB * NN * DD;
  float* cosm = tgn + (size_t)BB * NN * DD;
  float* selfm = cosm + (size_t)BB * NN * NN;
  int* tgt = (int*)(selfm + (size_t)BB * NN * NN);
  float* nll = (float*)(tgt + BB * NN);

  norm_kernel<<<2 * NROWS / 4, 256, 0, stream>>>(inputs, targets, ipn, tgn);
  gemm_kernel<<<dim3(16, BB, 2), 256, 0, stream>>>(ipn, tgn, cosm, selfm);
  hungarian_kernel<<<BB, 64, 0, stream>>>(cosm, tgt);
  nll_kernel<<<NROWS / 4, 256, 0, stream>>>(cosm, selfm, tgt, nll);
  reduce_kernel<<<1, 256, 0, stream>>>(nll, (float*)d_out);
}

// Round 3
// 1302.710 us; speedup vs baseline: 3.7380x; 2.4119x over previous
//
#include <hip/hip_runtime.h>
#include <hip/hip_fp16.h>
#include <math.h>

#define BB 128
#define NN 256
#define DD 64
constexpr int NROWS = BB * NN; // 32768

// ---------------- 1. L2 normalize (one wave per row of 64) ----------------
__global__ __launch_bounds__(256) void norm_kernel(const float* __restrict__ inp,
                                                   const float* __restrict__ tgin,
                                                   float* __restrict__ ipn,
                                                   float* __restrict__ tgn) {
  int wid = threadIdx.x >> 6;
  int lane = threadIdx.x & 63;
  int row = blockIdx.x * 4 + wid;   // 0 .. 2*NROWS-1
  const float* src;
  float* dst;
  int r = row;
  if (row < NROWS) { src = inp; dst = ipn; }
  else { src = tgin; dst = tgn; r = row - NROWS; }
  float x = src[(size_t)r * DD + lane];
  float s = x * x;
  #pragma unroll
  for (int off = 32; off; off >>= 1) s += __shfl_xor(s, off);
  float nrm = sqrtf(s);
  float scale = 1.0f / fmaxf(nrm, 1e-12f);
  dst[(size_t)r * DD + lane] = x * scale;
}

// ---------------- 2. batched fp32 GEMM: 64x64 tile, K=64 ----------------
__global__ __launch_bounds__(256) void gemm_kernel(const float* __restrict__ ipn,
                                                   const float* __restrict__ tgn,
                                                   float* __restrict__ cosm,
                                                   float* __restrict__ selfm) {
  __shared__ float As[64 * 64];  // [k][row] transposed
  __shared__ float Bs[64 * 64];
  int b = blockIdx.y;
  int ti = (blockIdx.x >> 2) * 64;
  int tj = (blockIdx.x & 3) * 64;
  const float* A = ipn + (size_t)b * NN * DD + (size_t)ti * DD;
  const float* Bm = (blockIdx.z ? ipn : tgn) + (size_t)b * NN * DD + (size_t)tj * DD;
  float* Out = (blockIdx.z ? selfm : cosm) + (size_t)b * NN * NN;
  int t = threadIdx.x;
  #pragma unroll
  for (int i = 0; i < 4; ++i) {
    int f4 = t + 256 * i;
    int row = f4 >> 4;
    int k0 = (f4 & 15) << 2;
    float4 a = reinterpret_cast<const float4*>(A)[f4];
    float4 v = reinterpret_cast<const float4*>(Bm)[f4];
    As[(k0 + 0) * 64 + row] = a.x; As[(k0 + 1) * 64 + row] = a.y;
    As[(k0 + 2) * 64 + row] = a.z; As[(k0 + 3) * 64 + row] = a.w;
    Bs[(k0 + 0) * 64 + row] = v.x; Bs[(k0 + 1) * 64 + row] = v.y;
    Bs[(k0 + 2) * 64 + row] = v.z; Bs[(k0 + 3) * 64 + row] = v.w;
  }
  __syncthreads();
  int tx = t & 15, ty = t >> 4;
  float acc[4][4] = {};
  #pragma unroll 8
  for (int k = 0; k < 64; ++k) {
    float4 av = *reinterpret_cast<const float4*>(&As[k * 64 + ty * 4]);
    float4 bv = *reinterpret_cast<const float4*>(&Bs[k * 64 + tx * 4]);
    float ar[4] = {av.x, av.y, av.z, av.w};
    float br[4] = {bv.x, bv.y, bv.z, bv.w};
    #pragma unroll
    for (int r = 0; r < 4; ++r)
      #pragma unroll
      for (int c = 0; c < 4; ++c)
        acc[r][c] = fmaf(ar[r], br[c], acc[r][c]);
  }
  #pragma unroll
  for (int r = 0; r < 4; ++r) {
    float4 o = {acc[r][0], acc[r][1], acc[r][2], acc[r][3]};
    *reinterpret_cast<float4*>(&Out[(size_t)(ti + ty * 4 + r) * NN + tj + tx * 4]) = o;
  }
}

// ---------------- 3. JV LSAP: one wave/batch, fp16 LDS cost, DPP argmin ----------------
__device__ __forceinline__ int sel4i(const int a[4], int q) {
  int r = a[0];
  if (q == 1) r = a[1];
  else if (q == 2) r = a[2];
  else if (q == 3) r = a[3];
  return r;
}
__device__ __forceinline__ void set4i(int a[4], int q, int v) {
  if (q == 0) a[0] = v;
  else if (q == 1) a[1] = v;
  else if (q == 2) a[2] = v;
  else a[3] = v;
}
__device__ __forceinline__ int readlane_i(int x, int l) {
  return __builtin_amdgcn_readlane(x, l);
}
__device__ __forceinline__ float readlane_f(float x, int l) {
  return __builtin_bit_cast(float, __builtin_amdgcn_readlane(__builtin_bit_cast(int, x), l));
}
// 64-lane min via DPP; global min lands in lane 63.
__device__ __forceinline__ float wave_min_f32(float x) {
  float t;
  #define DPP_STEP(ctrl)                                                            \
    t = __builtin_bit_cast(float, __builtin_amdgcn_update_dpp(                      \
            __builtin_bit_cast(int, x), __builtin_bit_cast(int, x), ctrl, 0xF, 0xF, \
            false));                                                                \
    x = fminf(x, t);
  DPP_STEP(0x111)  // row_shr:1
  DPP_STEP(0x112)  // row_shr:2
  DPP_STEP(0x114)  // row_shr:4
  DPP_STEP(0x118)  // row_shr:8
  DPP_STEP(0x142)  // row_bcast:15
  DPP_STEP(0x143)  // row_bcast:31
  #undef DPP_STEP
  return x;
}

__global__ __launch_bounds__(64) void hungarian_kernel(const float* __restrict__ cosm,
                                                       int* __restrict__ tgt) {
  const int b = blockIdx.x;
  const float* __restrict__ C = cosm + (size_t)b * NN * NN;
  __shared__ __half Cs[NN * NN];   // 128 KiB: cos in fp16
  __shared__ float u_lds[NN];      // row duals
  const int lane = threadIdx.x;    // 0..63
  const float FINF = INFINITY;

  // ---- stage cos -> fp16 LDS (coalesced float4 reads, ds_write_b64) ----
  const float4* Cf4 = reinterpret_cast<const float4*>(C);
  #pragma unroll 4
  for (int it = 0; it < NN * NN / 4 / 64; ++it) {
    float4 f = Cf4[it * 64 + lane];
    __half2 h01 = __floats2half2_rn(f.x, f.y);
    __half2 h23 = __floats2half2_rn(f.z, f.w);
    __half2* dst = reinterpret_cast<__half2*>(&Cs[(it * 64 + lane) * 4]);
    dst[0] = h01;
    dst[1] = h23;
  }
  #pragma unroll
  for (int q = 0; q < 4; ++q) u_lds[lane * 4 + q] = 0.f;
  // single wave: compiler inserts lgkmcnt waits before first use

  float v[4] = {0.f, 0.f, 0.f, 0.f};  // col duals (col = lane*4+q)
  int p[4] = {0, 0, 0, 0};            // row assigned to col (1-based, 0 = free)

  for (int i = 1; i <= NN; ++i) {
    float minv[4] = {FINF, FINF, FINF, FINF};  // absolute shortest distances
    int way[4] = {-2, -2, -2, -2};
    int usedm = 0;
    float Delta = 0.f;
    int j0 = -1;
    float u_i0 = 0.f;
    int row = i - 1;
    uint2 raw = *reinterpret_cast<const uint2*>(&Cs[(size_t)row * NN + lane * 4]);
    int jf;

    while (true) {
      __half2 h01 = __builtin_bit_cast(__half2, raw.x);
      __half2 h23 = __builtin_bit_cast(__half2, raw.y);
      float2 f01 = __half22float2(h01);
      float2 f23 = __half22float2(h23);
      float cc[4] = {f01.x, f01.y, f23.x, f23.y};
      float t0 = Delta - u_i0;
      float cand[4];
      #pragma unroll
      for (int q = 0; q < 4; ++q) {
        float dnew = t0 - cc[q] - v[q];   // cost = -cos
        bool freeq = !((usedm >> q) & 1);
        if (freeq && dnew < minv[q]) { minv[q] = dnew; way[q] = j0; }
        cand[q] = freeq ? minv[q] : FINF;
      }
      // local argmin (strict < keeps lowest q on ties)
      float bv = cand[0];
      int bc = lane * 4;
      #pragma unroll
      for (int q = 1; q < 4; ++q)
        if (cand[q] < bv) { bv = cand[q]; bc = lane * 4 + q; }
      // wave argmin: DPP value-min, then first lane matching (lowest col)
      float m = wave_min_f32(bv);
      float K = readlane_f(m, 63);
      unsigned long long mask = __ballot(bv == K);
      int l0 = __ffsll(mask) - 1;
      int j1 = readlane_i(bc, l0);
      Delta = K;
      int pnext = readlane_i(sel4i(p, j1 & 3), j1 >> 2);
      if (pnext == 0) { jf = j1; break; }
      if (lane == (j1 >> 2)) usedm |= 1 << (j1 & 3);
      j0 = j1;
      row = pnext - 1;
      raw = *reinterpret_cast<const uint2*>(&Cs[(size_t)row * NN + lane * 4]);
      u_i0 = u_lds[row];  // phase-start dual (updates happen at phase end)
    }

    // phase-end dual updates (used cols only; jf excluded)
    #pragma unroll
    for (int q = 0; q < 4; ++q) {
      if ((usedm >> q) & 1) {
        float dd = Delta - minv[q];
        v[q] -= dd;
        u_lds[p[q] - 1] += dd;   // rows distinct across lanes: no collision
      }
    }
    if (lane == 0) u_lds[i - 1] = Delta;  // phase row: u was 0

    // augmentation walk (uniform, readlane broadcasts)
    int j = jf;
    while (true) {
      int w = readlane_i(sel4i(way, j & 3), j >> 2);  // way[j]
      int newv;
      if (w < 0) newv = i;
      else newv = readlane_i(sel4i(p, w & 3), w >> 2);  // old p[way[j]]
      if (lane == (j >> 2)) set4i(p, j & 3, newv);
      if (w < 0) break;
      j = w;
    }
  }
  // col4row[p[j]-1] = j
  #pragma unroll
  for (int q = 0; q < 4; ++q)
    tgt[(size_t)b * NN + (p[q] - 1)] = lane * 4 + q;
}

// ---------------- 4. fused log-softmax + NLL (one wave per row) ----------------
__global__ __launch_bounds__(256) void nll_kernel(const float* __restrict__ cosm,
                                                  const float* __restrict__ selfm,
                                                  const int* __restrict__ tgt,
                                                  float* __restrict__ nll) {
  int lane = threadIdx.x & 63, wid = threadIdx.x >> 6;
  int row = blockIdx.x * 4 + wid;
  int r = row & (NN - 1);
  const float* crow = cosm + (size_t)row * NN;
  const float* srow = selfm + (size_t)row * NN;
  float xc[4], xs[4];
  float m = -INFINITY;
  #pragma unroll
  for (int q = 0; q < 4; ++q) {
    int j = lane + 64 * q;
    xc[q] = crow[j];
    xs[q] = (j == r) ? -INFINITY : srow[j];
    m = fmaxf(m, fmaxf(xc[q], xs[q]));
  }
  #pragma unroll
  for (int off = 32; off; off >>= 1) m = fmaxf(m, __shfl_xor(m, off));
  float s = 0.f;
  #pragma unroll
  for (int q = 0; q < 4; ++q) {
    s += expf(xc[q] - m);
    s += (xs[q] == -INFINITY) ? 0.f : expf(xs[q] - m);
  }
  #pragma unroll
  for (int off = 32; off; off >>= 1) s += __shfl_xor(s, off);
  if (lane == 0) {
    float lse = m + logf(s);
    nll[row] = lse - crow[tgt[row]];
  }
}

// ---------------- 5. deterministic mean reduce ----------------
__global__ __launch_bounds__(256) void reduce_kernel(const float* __restrict__ nll,
                                                     float* __restrict__ out) {
  __shared__ float sm[256];
  int t = threadIdx.x;
  float s = 0.f;
  for (int i = t; i < NROWS; i += 256) s += nll[i];
  sm[t] = s;
  __syncthreads();
  for (int st = 128; st; st >>= 1) {
    if (t < st) sm[t] += sm[t + st];
    __syncthreads();
  }
  if (t == 0) out[0] = sm[0] / (float)NROWS;
}

extern "C" void kernel_launch(void* const* d_in, const int* in_sizes, int n_in,
                              void* d_out, int out_size, void* d_ws, size_t ws_size,
                              hipStream_t stream) {
  const float* inputs = (const float*)d_in[0];
  const float* targets = (const float*)d_in[1];
  float* ws = (float*)d_ws;
  float* ipn = ws;
  float* tgn = ipn + (size_t)BB * NN * DD;
  float* cosm = tgn + (size_t)BB * NN * DD;
  float* selfm = cosm + (size_t)BB * NN * NN;
  int* tgt = (int*)(selfm + (size_t)BB * NN * NN);
  float* nll = (float*)(tgt + BB * NN);

  norm_kernel<<<2 * NROWS / 4, 256, 0, stream>>>(inputs, targets, ipn, tgn);
  gemm_kernel<<<dim3(16, BB, 2), 256, 0, stream>>>(ipn, tgn, cosm, selfm);
  hungarian_kernel<<<BB, 64, 0, stream>>>(cosm, tgt);
  nll_kernel<<<NROWS / 4, 256, 0, stream>>>(cosm, selfm, tgt, nll);
  reduce_kernel<<<1, 256, 0, stream>>>(nll, (float*)d_out);
}

// Round 6
// 1282.728 us; speedup vs baseline: 3.7962x; 1.0156x over previous
//
#include <hip/hip_runtime.h>
#include <math.h>

#define BB 128
#define NN 256
#define DD 64
constexpr int NROWS = BB * NN; // 32768

// ---------------- 1. L2 normalize (one wave per row of 64) ----------------
__global__ __launch_bounds__(256) void norm_kernel(const float* __restrict__ inp,
                                                   const float* __restrict__ tgin,
                                                   float* __restrict__ ipn,
                                                   float* __restrict__ tgn) {
  int wid = threadIdx.x >> 6;
  int lane = threadIdx.x & 63;
  int row = blockIdx.x * 4 + wid;   // 0 .. 2*NROWS-1
  const float* src;
  float* dst;
  int r = row;
  if (row < NROWS) { src = inp; dst = ipn; }
  else { src = tgin; dst = tgn; r = row - NROWS; }
  float x = src[(size_t)r * DD + lane];
  float s = x * x;
  #pragma unroll
  for (int off = 32; off; off >>= 1) s += __shfl_xor(s, off);
  float nrm = sqrtf(s);
  float scale = 1.0f / fmaxf(nrm, 1e-12f);
  dst[(size_t)r * DD + lane] = x * scale;
}

// ---------------- 2. batched fp32 GEMM: 64x64 tile, K=64 ----------------
__global__ __launch_bounds__(256) void gemm_kernel(const float* __restrict__ ipn,
                                                   const float* __restrict__ tgn,
                                                   float* __restrict__ cosm,
                                                   float* __restrict__ selfm) {
  __shared__ float As[64 * 64];  // [k][row] transposed
  __shared__ float Bs[64 * 64];
  int b = blockIdx.y;
  int ti = (blockIdx.x >> 2) * 64;
  int tj = (blockIdx.x & 3) * 64;
  const float* A = ipn + (size_t)b * NN * DD + (size_t)ti * DD;
  const float* Bm = (blockIdx.z ? ipn : tgn) + (size_t)b * NN * DD + (size_t)tj * DD;
  float* Out = (blockIdx.z ? selfm : cosm) + (size_t)b * NN * NN;
  int t = threadIdx.x;
  #pragma unroll
  for (int i = 0; i < 4; ++i) {
    int f4 = t + 256 * i;
    int row = f4 >> 4;
    int k0 = (f4 & 15) << 2;
    float4 a = reinterpret_cast<const float4*>(A)[f4];
    float4 v = reinterpret_cast<const float4*>(Bm)[f4];
    As[(k0 + 0) * 64 + row] = a.x; As[(k0 + 1) * 64 + row] = a.y;
    As[(k0 + 2) * 64 + row] = a.z; As[(k0 + 3) * 64 + row] = a.w;
    Bs[(k0 + 0) * 64 + row] = v.x; Bs[(k0 + 1) * 64 + row] = v.y;
    Bs[(k0 + 2) * 64 + row] = v.z; Bs[(k0 + 3) * 64 + row] = v.w;
  }
  __syncthreads();
  int tx = t & 15, ty = t >> 4;
  float acc[4][4] = {};
  #pragma unroll 8
  for (int k = 0; k < 64; ++k) {
    float4 av = *reinterpret_cast<const float4*>(&As[k * 64 + ty * 4]);
    float4 bv = *reinterpret_cast<const float4*>(&Bs[k * 64 + tx * 4]);
    float ar[4] = {av.x, av.y, av.z, av.w};
    float br[4] = {bv.x, bv.y, bv.z, bv.w};
    #pragma unroll
    for (int r = 0; r < 4; ++r)
      #pragma unroll
      for (int c = 0; c < 4; ++c)
        acc[r][c] = fmaf(ar[r], br[c], acc[r][c]);
  }
  #pragma unroll
  for (int r = 0; r < 4; ++r) {
    float4 o = {acc[r][0], acc[r][1], acc[r][2], acc[r][3]};
    *reinterpret_cast<float4*>(&Out[(size_t)(ti + ty * 4 + r) * NN + tj + tx * 4]) = o;
  }
}

// ---------------- 3. JV LSAP: one wave/batch, EXACT integer fixed-point ----------------
// Cost quantized ONCE to u16 grid (2^-15); all dual/distance arithmetic in exact
// int => solver exactly optimal for the quantized problem (like fp16 in R3, but
// finer grid). key = (dist<<8)|col is an EXACT lexicographic argmin key.
__device__ __forceinline__ int sel4i(const int a[4], int q) {
  int r = a[0];
  if (q == 1) r = a[1];
  else if (q == 2) r = a[2];
  else if (q == 3) r = a[3];
  return r;
}
__device__ __forceinline__ void set4i(int a[4], int q, int v) {
  if (q == 0) a[0] = v;
  else if (q == 1) a[1] = v;
  else if (q == 2) a[2] = v;
  else a[3] = v;
}
__device__ __forceinline__ int readlane_i(int x, int l) {
  return __builtin_amdgcn_readlane(x, l);
}
// 64-lane unsigned min via DPP; global min lands in lane 63.
__device__ __forceinline__ unsigned wave_min_u32(unsigned x) {
  unsigned t;
  #define DPP_STEP(ctrl)                                                        \
    t = (unsigned)__builtin_amdgcn_update_dpp((int)x, (int)x, ctrl, 0xF, 0xF,   \
                                              false);                           \
    x = (t < x) ? t : x;
  DPP_STEP(0x111)  // row_shr:1
  DPP_STEP(0x112)  // row_shr:2
  DPP_STEP(0x114)  // row_shr:4
  DPP_STEP(0x118)  // row_shr:8
  DPP_STEP(0x142)  // row_bcast:15
  DPP_STEP(0x143)  // row_bcast:31
  #undef DPP_STEP
  return x;
}

__global__ __launch_bounds__(64) void hungarian_kernel(const float* __restrict__ cosm,
                                                       int* __restrict__ tgt) {
  const int b = blockIdx.x;
  const float* __restrict__ C = cosm + (size_t)b * NN * NN;
  __shared__ unsigned short Cs[NN * NN];  // 128 KiB: u16 fixed-point cost
  __shared__ int u_lds[NN];               // row duals (int)
  const int lane = threadIdx.x;           // 0..63
  const int col0 = lane * 4;

  // ---- stage: C_int = clamp(round((1 - cos) * 32768), 0, 65535) ----
  const float4* Cf4 = reinterpret_cast<const float4*>(C);
  #pragma unroll 4
  for (int it = 0; it < NN * NN / 4 / 64; ++it) {
    float4 f = Cf4[it * 64 + lane];
    unsigned u0 = __float2uint_rn(fmaxf(32768.f - f.x * 32768.f, 0.f));
    unsigned u1 = __float2uint_rn(fmaxf(32768.f - f.y * 32768.f, 0.f));
    unsigned u2 = __float2uint_rn(fmaxf(32768.f - f.z * 32768.f, 0.f));
    unsigned u3 = __float2uint_rn(fmaxf(32768.f - f.w * 32768.f, 0.f));
    u0 = u0 > 65535u ? 65535u : u0;
    u1 = u1 > 65535u ? 65535u : u1;
    u2 = u2 > 65535u ? 65535u : u2;
    u3 = u3 > 65535u ? 65535u : u3;
    uint2 packed;
    packed.x = u0 | (u1 << 16);
    packed.y = u2 | (u3 << 16);
    *reinterpret_cast<uint2*>(&Cs[(it * 64 + lane) * 4]) = packed;
  }
  #pragma unroll
  for (int q = 0; q < 4; ++q) u_lds[col0 + q] = 0;
  // single wave: compiler inserts lgkmcnt waits before first use

  int vv[4];                     // vv[q] = colq - (v[q] << 8)  (v starts at 0)
  #pragma unroll
  for (int q = 0; q < 4; ++q) vv[q] = col0 + q;
  int p[4] = {0, 0, 0, 0};       // row assigned to col (1-based, 0 = free)

  for (int i = 1; i <= NN; ++i) {
    unsigned key[4] = {0xFFFFFFFFu, 0xFFFFFFFFu, 0xFFFFFFFFu, 0xFFFFFFFFu};
    int way[4] = {-1, -1, -1, -1};
    int usedm = 0;
    int Delta = 0;
    int j0 = -1;
    int u_i0 = 0;
    int row = i - 1;
    uint2 raw = *reinterpret_cast<const uint2*>(&Cs[(size_t)row * NN + col0]);
    int jf;

    while (true) {
      int t0s8 = (Delta - u_i0) << 8;
      // unpack costs pre-shifted by 8
      int cs[4];
      cs[0] = (int)((raw.x & 0xFFFFu) << 8);
      cs[1] = (int)((raw.x >> 8) & 0x00FFFF00u);
      cs[2] = (int)((raw.y & 0xFFFFu) << 8);
      cs[3] = (int)((raw.y >> 8) & 0x00FFFF00u);
      #pragma unroll
      for (int q = 0; q < 4; ++q) {
        unsigned nk = (unsigned)(t0s8 + cs[q] + vv[q]);  // (dist<<8)|col, exact
        if (nk < key[q]) { key[q] = nk; way[q] = j0; }
      }
      unsigned c0 = (usedm & 1) ? 0xFFFFFFFFu : key[0];
      unsigned c1 = (usedm & 2) ? 0xFFFFFFFFu : key[1];
      unsigned c2 = (usedm & 4) ? 0xFFFFFFFFu : key[2];
      unsigned c3 = (usedm & 8) ? 0xFFFFFFFFu : key[3];
      unsigned loc = c0 < c1 ? c0 : c1;
      unsigned l2 = c2 < c3 ? c2 : c3;
      loc = loc < l2 ? loc : l2;
      unsigned K = (unsigned)readlane_i((int)wave_min_u32(loc), 63);
      int j1 = (int)(K & 0xFFu);
      Delta = (int)(K >> 8);                 // EXACT (integer key)
      int pnext = readlane_i(sel4i(p, j1 & 3), j1 >> 2);
      if (pnext == 0) { jf = j1; break; }
      row = pnext - 1;
      raw = *reinterpret_cast<const uint2*>(&Cs[(size_t)row * NN + col0]);
      u_i0 = u_lds[row];
      if (lane == (j1 >> 2)) usedm |= 1 << (j1 & 3);
      j0 = j1;
    }

    // phase-end dual updates (used cols only; jf excluded) — exact int
    #pragma unroll
    for (int q = 0; q < 4; ++q) {
      if ((usedm >> q) & 1) {
        int dd = Delta - (int)(key[q] >> 8);
        vv[q] += dd << 8;                 // v[q] -= dd
        u_lds[p[q] - 1] += dd;            // rows distinct across lanes
      }
    }
    if (lane == 0) u_lds[i - 1] = Delta;  // phase row: u was 0

    // augmentation walk (uniform, readlane broadcasts)
    int j = jf;
    while (true) {
      int w = readlane_i(sel4i(way, j & 3), j >> 2);  // way[j]
      int newv;
      if (w < 0) newv = i;
      else newv = readlane_i(sel4i(p, w & 3), w >> 2);  // old p[way[j]]
      if (lane == (j >> 2)) set4i(p, j & 3, newv);
      if (w < 0) break;
      j = w;
    }
  }
  // col4row[p[j]-1] = j
  #pragma unroll
  for (int q = 0; q < 4; ++q)
    tgt[(size_t)b * NN + (p[q] - 1)] = col0 + q;
}

// ---------------- 4. fused log-softmax + NLL (one wave per row) ----------------
__global__ __launch_bounds__(256) void nll_kernel(const float* __restrict__ cosm,
                                                  const float* __restrict__ selfm,
                                                  const int* __restrict__ tgt,
                                                  float* __restrict__ nll) {
  int lane = threadIdx.x & 63, wid = threadIdx.x >> 6;
  int row = blockIdx.x * 4 + wid;
  int r = row & (NN - 1);
  const float* crow = cosm + (size_t)row * NN;
  const float* srow = selfm + (size_t)row * NN;
  float xc[4], xs[4];
  float m = -INFINITY;
  #pragma unroll
  for (int q = 0; q < 4; ++q) {
    int j = lane + 64 * q;
    xc[q] = crow[j];
    xs[q] = (j == r) ? -INFINITY : srow[j];
    m = fmaxf(m, fmaxf(xc[q], xs[q]));
  }
  #pragma unroll
  for (int off = 32; off; off >>= 1) m = fmaxf(m, __shfl_xor(m, off));
  float s = 0.f;
  #pragma unroll
  for (int q = 0; q < 4; ++q) {
    s += expf(xc[q] - m);
    s += (xs[q] == -INFINITY) ? 0.f : expf(xs[q] - m);
  }
  #pragma unroll
  for (int off = 32; off; off >>= 1) s += __shfl_xor(s, off);
  if (lane == 0) {
    float lse = m + logf(s);
    nll[row] = lse - crow[tgt[row]];
  }
}

// ---------------- 5. deterministic mean reduce ----------------
__global__ __launch_bounds__(256) void reduce_kernel(const float* __restrict__ nll,
                                                     float* __restrict__ out) {
  __shared__ float sm[256];
  int t = threadIdx.x;
  float s = 0.f;
  for (int i = t; i < NROWS; i += 256) s += nll[i];
  sm[t] = s;
  __syncthreads();
  for (int st = 128; st; st >>= 1) {
    if (t < st) sm[t] += sm[t + st];
    __syncthreads();
  }
  if (t == 0) out[0] = sm[0] / (float)NROWS;
}

extern "C" void kernel_launch(void* const* d_in, const int* in_sizes, int n_in,
                              void* d_out, int out_size, void* d_ws, size_t ws_size,
                              hipStream_t stream) {
  const float* inputs = (const float*)d_in[0];
  const float* targets = (const float*)d_in[1];
  float* ws = (float*)d_ws;
  float* ipn = ws;
  float* tgn = ipn + (size_t)BB * NN * DD;
  float* cosm = tgn + (size_t)BB * NN * DD;
  float* selfm = cosm + (size_t)BB * NN * NN;
  int* tgt = (int*)(selfm + (size_t)BB * NN * NN);
  float* nll = (float*)(tgt + BB * NN);

  norm_kernel<<<2 * NROWS / 4, 256, 0, stream>>>(inputs, targets, ipn, tgn);
  gemm_kernel<<<dim3(16, BB, 2), 256, 0, stream>>>(ipn, tgn, cosm, selfm);
  hungarian_kernel<<<BB, 64, 0, stream>>>(cosm, tgt);
  nll_kernel<<<NROWS / 4, 256, 0, stream>>>(cosm, selfm, tgt, nll);
  reduce_kernel<<<1, 256, 0, stream>>>(nll, (float*)d_out);
}